// Round 3
// baseline (305.346 us; speedup 1.0000x reference)
//
#include <hip/hip_runtime.h>

// CenterLoss: B=32, T=256, D=96, C=6625, N=B*T=8192.
// loss = mean_n clip(||f_n - centers[argmax_c predicts[n,c]]||^2, EPS, INF)
//        + (C-1)*EPS      // masked-out zeros each clip up to EPS
//
// Memory-bound floor: 8192*6625*4B ~= 217 MB -> ~35 us @ 6.3 TB/s (all inputs
// ~223 MB fit L3, so steady-state may be faster still).
// Prior best 305.9 us (~11% of achievable BW) => latency/pipeline-bound, not BW.
// R4 (third submit, never measured -- 3x GPU acquisition timeout):
//  (a) 8-deep explicit load batching: 8 independent global_load_dwordx4 in
//      flight per wave (128 B/lane) before any compare consumes them.
//  (b) max-tree per float4 + guarded index fixup -- cuts the loop-carried
//      best/bidx dependent chain ~4x and VALU per element ~3x; strict `>`
//      with monotone indices preserves jnp.argmax first-max tie semantics.
// Structure otherwise identical to R3 (wave-per-row, one atomic per block).

#define EPS_F 1e-7f
#define INF_F 1e11f

constexpr int C_DIM = 6625;
constexpr int D_DIM = 96;
constexpr int N_ROWS = 8192;
constexpr int ROWS_PER_BLOCK = 4;   // one 64-lane wave per row

__global__ __launch_bounds__(256) void center_loss_fused(
    const float* __restrict__ feats,      // [N, 96]
    const float* __restrict__ predicts,   // [N, 6625]
    const float* __restrict__ centers,    // [6625, 96]
    float* __restrict__ out)              // [1]
{
    const int wave = threadIdx.x >> 6;
    const int lane = threadIdx.x & 63;
    const int n = blockIdx.x * ROWS_PER_BLOCK + wave;

    const float* __restrict__ row = predicts + (size_t)n * C_DIM;

    float best = -3.4e38f;
    int   bidx = 0;

    // Row stride 6625 floats -> row base misalignment cycles n%4 elements.
    // Peel to 16B so the bulk runs as global_load_dwordx4.
    const int mis    = (int)(((size_t)n * (size_t)C_DIM) & 3);
    const int prefix = (4 - mis) & 3;
    if (lane < prefix) {
        float v = row[lane];
        if (v > best) { best = v; bidx = lane; }
    }
    const int nvec = (C_DIM - prefix) >> 2;   // 1655 or 1656
    const float4* __restrict__ vrow = (const float4*)(row + prefix);

    // ---- main: batches of 8 float4 per lane; all 8 loads issued before use.
    constexpr int BATCH = 8;
    const int main_end = (nvec / (64 * BATCH)) * (64 * BATCH);  // 1536
    for (int kb = lane; kb < main_end; kb += 64 * BATCH) {
        float4 v[BATCH];
        #pragma unroll
        for (int i = 0; i < BATCH; ++i) v[i] = vrow[kb + i * 64];
        #pragma unroll
        for (int i = 0; i < BATCH; ++i) {
            const float4 w = v[i];
            const int c0 = prefix + 4 * (kb + i * 64);
            // short loop-carried chain: one fmax-tree + one compare per float4
            const float m = fmaxf(fmaxf(w.x, w.y), fmaxf(w.z, w.w));
            if (m > best) {   // strict > keeps earliest index within a lane
                best = m;
                bidx = (w.x == m) ? c0
                     : (w.y == m) ? (c0 + 1)
                     : (w.z == m) ? (c0 + 2)
                     :              (c0 + 3);
            }
        }
    }
    // ---- remainder float4s (k in [main_end, nvec), 1-2 iters per lane)
    for (int k = main_end + lane; k < nvec; k += 64) {
        const float4 w = vrow[k];
        const int c0 = prefix + 4 * k;
        const float m = fmaxf(fmaxf(w.x, w.y), fmaxf(w.z, w.w));
        if (m > best) {
            best = m;
            bidx = (w.x == m) ? c0
                 : (w.y == m) ? (c0 + 1)
                 : (w.z == m) ? (c0 + 2)
                 :              (c0 + 3);
        }
    }
    // ---- scalar tail ((C_DIM - prefix) % 4 elements)
    const int tail_start = prefix + 4 * nvec;
    if (lane < C_DIM - tail_start) {
        int c = tail_start + lane;
        float v = row[c];
        if (v > best) { best = v; bidx = c; }
    }

    // 64-lane argmax reduce, tie -> smaller index (matches jnp.argmax).
    #pragma unroll
    for (int off = 32; off > 0; off >>= 1) {
        float ov = __shfl_down(best, off);
        int   oi = __shfl_down(bidx, off);
        if (ov > best || (ov == best && oi < bidx)) { best = ov; bidx = oi; }
    }
    const int label = __shfl(bidx, 0);

    // Squared distance: lanes 0..63 cover dims 0..63; lanes 0..31 also 64..95.
    const float* __restrict__ f = feats   + (size_t)n     * D_DIM;
    const float* __restrict__ c = centers + (size_t)label * D_DIM;
    float diff = f[lane] - c[lane];
    float s = diff * diff;
    if (lane < D_DIM - 64) {
        float d2 = f[lane + 64] - c[lane + 64];
        s += d2 * d2;
    }
    #pragma unroll
    for (int off = 32; off > 0; off >>= 1) s += __shfl_down(s, off);

    // Per-block reduce of the 4 wave distances, one atomic per block.
    __shared__ float s_part[ROWS_PER_BLOCK];
    if (lane == 0) s_part[wave] = fminf(fmaxf(s, EPS_F), INF_F);
    __syncthreads();
    if (threadIdx.x == 0) {
        float bs = s_part[0] + s_part[1] + s_part[2] + s_part[3];
        float add = bs * (1.0f / (float)N_ROWS);
        if (blockIdx.x == 0) add += (float)(C_DIM - 1) * EPS_F;
        atomicAdd(out, add);   // device-scope; d_out poison -3e-13f is negligible
    }
}

extern "C" void kernel_launch(void* const* d_in, const int* in_sizes, int n_in,
                              void* d_out, int out_size, void* d_ws, size_t ws_size,
                              hipStream_t stream) {
    const float* feats    = (const float*)d_in[0];  // [32,256,96]
    const float* predicts = (const float*)d_in[1];  // [32,256,6625]
    const float* centers  = (const float*)d_in[2];  // [6625,96]
    float* out = (float*)d_out;
    (void)d_ws; (void)ws_size;

    const int N = in_sizes[0] / D_DIM;  // 8192
    center_loss_fused<<<N / ROWS_PER_BLOCK, 256, 0, stream>>>(feats, predicts, centers, out);
}